// Round 6
// baseline (1125.756 us; speedup 1.0000x reference)
//
#include <hip/hip_runtime.h>

// ---------- bf16 helpers (raw ushort representation) ----------
__device__ __forceinline__ float b2f(ushort u) {
    union { float f; unsigned int i; } w; w.i = ((unsigned int)u) << 16; return w.f;
}
__device__ __forceinline__ ushort f2b(float f) {
    union { float f; unsigned int i; } w; w.f = f;
    unsigned int lsb = (w.i >> 16) & 1u;
    w.i += 0x7fffu + lsb;
    return (ushort)(w.i >> 16);
}

typedef __bf16 bf16x8 __attribute__((ext_vector_type(8)));
typedef float floatx4 __attribute__((ext_vector_type(4)));

// async global->LDS, 16B per lane; lane i lands at lds_base + i*16B (HW rule)
__device__ __forceinline__ void async_copy16(ushort* lds_base, const ushort* gptr) {
    __builtin_amdgcn_global_load_lds(
        (const __attribute__((address_space(1))) unsigned int*)gptr,
        (__attribute__((address_space(3))) unsigned int*)lds_base,
        16, 0, 0);
}

// Problem constants
#define BATCH 16
#define NTOK  3136
#define NHEAD 8
#define HDIM  64
#define HSP   56
#define MROWS (BATCH * NTOK)   // 50176
#define KDIM  512              // both GEMMs have K = 512

// ---------- dtype detection ----------
__global__ __launch_bounds__(256) void detect_dtype(const ushort* __restrict__ x,
                                                    int* __restrict__ flag)
{
    __shared__ int s;
    if (threadIdx.x == 0) s = 0;
    __syncthreads();
    int bad = 0;
    for (int i = threadIdx.x; i < 4096; i += 256) {
        int e = (x[i] >> 7) & 0xFF;
        if (e >= 0x90) bad = 1;
    }
    if (bad) s = 1;
    __syncthreads();
    if (threadIdx.x == 0) flag[0] = s;   // 1 => inputs are fp32
}

// ---------- convert x -> bf16 ----------
__global__ __launch_bounds__(256) void convert_x(
    const void* __restrict__ x, const int* __restrict__ flag,
    ushort* __restrict__ xbf)
{
    size_t t = (size_t)blockIdx.x * 256 + threadIdx.x;
    if (flag[0]) {
        const float* xf = (const float*)x + t * 8;
        float4 f0 = *(const float4*)xf;
        float4 f1 = *(const float4*)(xf + 4);
        ushort o[8] = { f2b(f0.x), f2b(f0.y), f2b(f0.z), f2b(f0.w),
                        f2b(f1.x), f2b(f1.y), f2b(f1.z), f2b(f1.w) };
        *(uint4*)(xbf + t * 8) = *(const uint4*)o;
    } else {
        *(uint4*)(xbf + t * 8) = *((const uint4*)x + t);
    }
}

// ---------- weight transpose ----------
__global__ __launch_bounds__(256) void prep_weights(
    const void* __restrict__ Wq, const void* __restrict__ Wkv,
    const void* __restrict__ Wp, const int* __restrict__ flag,
    ushort* __restrict__ WqkvT, ushort* __restrict__ WpT)
{
    bool f32 = flag[0] != 0;
    int idx = blockIdx.x * 256 + threadIdx.x;
    int kk = idx & 511;
    int n  = idx >> 9;
    if (n < 1536) {
        ushort val;
        if (n < 512)
            val = f32 ? f2b(((const float*)Wq)[kk * 512 + n])
                      : ((const ushort*)Wq)[kk * 512 + n];
        else
            val = f32 ? f2b(((const float*)Wkv)[kk * 1024 + (n - 512)])
                      : ((const ushort*)Wkv)[kk * 1024 + (n - 512)];
        WqkvT[n * 512 + kk] = val;
    } else {
        int n2 = n - 1536;
        WpT[n2 * 512 + kk] = f32 ? f2b(((const float*)Wp)[kk * 512 + n2])
                                 : ((const ushort*)Wp)[kk * 512 + n2];
    }
}

// ---------- prep dwc weights ----------
__global__ __launch_bounds__(256) void prep_dwc(
    const void* __restrict__ dwc_w, const void* __restrict__ dwc_b,
    const int* __restrict__ flag, float* __restrict__ wT)
{
    bool f32 = flag[0] != 0;
    for (int i = threadIdx.x; i < 1600; i += 256) {
        int e = i / 25, tap = i % 25;
        float w = f32 ? ((const float*)dwc_w)[i] : b2f(((const ushort*)dwc_w)[i]);
        wT[tap * 64 + e] = w;
    }
    if (threadIdx.x < 64) {
        float b = f32 ? ((const float*)dwc_b)[threadIdx.x]
                      : b2f(((const ushort*)dwc_b)[threadIdx.x]);
        wT[1600 + threadIdx.x] = b;
    }
}

__device__ __forceinline__ int swz(int r) { return (r ^ (r >> 2)) & 3; }

// ============================================================================
// 256x256 8-wave GEMM, BK=64, m201-style 4-phase schedule, deep prefetch.
// (identical to R5 — see that round's ledger comments)
// ============================================================================
#define VMWAIT(N) asm volatile("s_waitcnt vmcnt(" #N ")" ::: "memory")
#define LGKM0()   do { asm volatile("s_waitcnt lgkmcnt(0)" ::: "memory"); \
                       __builtin_amdgcn_sched_barrier(0); } while (0)
#define ASLOT(u,h) ((((u) & 1) * 2 + (h)) * 8192)
#define BSLOT(u,h) (32768 + (((u) & 1) * 2 + (h)) * 8192)

__global__ __launch_bounds__(512, 2) void gemm256_bt(
    const ushort* __restrict__ A, const ushort* __restrict__ Bt,
    int mode, const int* __restrict__ flag,
    const void* __restrict__ pos_enc, const void* __restrict__ bias,
    void* __restrict__ out0, ushort* __restrict__ out1, ushort* __restrict__ out2,
    int ntn)
{
    __shared__ ushort smem[65536];   // 128 KiB

    const bool f32 = flag[0] != 0;
    const int tid = threadIdx.x;
    const int lam = tid & 63;
    const int w   = tid >> 6;        // 0..7
    const int wm  = w >> 2;          // 0..1 (M half)
    const int wn  = w & 3;           // 0..3 (N quarter)
    const int g    = lam >> 4;       // 0..3
    const int mrow = lam & 15;

    // XCD-aware bijective swizzle, tm-major (consecutive fid share A-panel)
    const int nwg = gridDim.x;
    const int q8  = nwg >> 3;
    const int bid = blockIdx.x;
    const int fid = (bid & 7) * q8 + (bid >> 3);
    const int tm = fid / ntn, tn = fid - tm * ntn;
    const int m0 = tm * 256, n0 = tn * 256;

    // staging: per-lane pointers, inverse-swizzled global column (R1-proven)
    const int srow  = w * 16 + (lam >> 3);            // row within 128-row half
    const int scol8 = 8 * ((lam & 7) ^ (lam >> 3));   // pre-swizzled col (elems)
    const ushort* gA0 = A  + (size_t)(m0 +       srow) * KDIM + scol8;
    const ushort* gA1 = A  + (size_t)(m0 + 128 + srow) * KDIM + scol8;
    const ushort* gB0 = Bt + (size_t)(n0 +       srow) * KDIM + scol8;
    const ushort* gB1 = Bt + (size_t)(n0 + 128 + srow) * KDIM + scol8;

    // fragment read offsets (ushort units): row r -> r*64 + ((c ^ (r&7))*8)
    const int m7  = mrow & 7;
    const int kx0 = 8 * (g ^ m7);          // k-step 0 (chunks 0..3)
    const int kx1 = 8 * ((4 + g) ^ m7);    // k-step 1 (chunks 4..7)
    const int aRow = mrow * 64;                         // + fr*1024
    const int bRow = ((wn & 1) * 64 + mrow) * 64;       // + fc*1024

    floatx4 acc[8][4];
    #pragma unroll
    for (int i = 0; i < 8; i++)
        #pragma unroll
        for (int j = 0; j < 4; j++) acc[i][j] = (floatx4)0.f;

#define STG(gp, sb, ko) do { \
    async_copy16(smem + (sb) + w * 1024,       (gp) + (ko)); \
    async_copy16(smem + (sb) + w * 1024 + 512, (gp) + 4096 + (ko)); } while (0)

    // prologue: K-tiles 0 and 1
    STG(gA0, ASLOT(0,0), 0);  STG(gA1, ASLOT(0,1), 0);
    STG(gB0, BSLOT(0,0), 0);  STG(gB1, BSLOT(0,1), 0);
    STG(gA0, ASLOT(1,0), 64); STG(gA1, ASLOT(1,1), 64);
    STG(gB0, BSLOT(1,0), 64); STG(gB1, BSLOT(1,1), 64);
    VMWAIT(8);                       // A(0),B(0) landed (K-tile 1 in flight)
    __builtin_amdgcn_s_barrier();

    bf16x8 a[2][2], bb[4][2];

#define PHASE_MFMA(P) do { \
    __builtin_amdgcn_s_setprio(1); \
    _Pragma("unroll") \
    for (int q = 0; q < 2; ++q) \
        _Pragma("unroll") \
        for (int fc = 0; fc < 4; ++fc) { \
            acc[2*(P)+q][fc] = __builtin_amdgcn_mfma_f32_16x16x32_bf16( \
                a[q][0], bb[fc][0], acc[2*(P)+q][fc], 0, 0, 0); \
            acc[2*(P)+q][fc] = __builtin_amdgcn_mfma_f32_16x16x32_bf16( \
                a[q][1], bb[fc][1], acc[2*(P)+q][fc], 0, 0, 0); \
        } \
    __builtin_amdgcn_s_setprio(0); } while (0)

    #pragma unroll
    for (int u = 0; u < 8; ++u) {
        const ushort* sa = smem + ASLOT(u, wm) + aRow;
        const ushort* sb = smem + BSLOT(u, (wn >> 1)) + bRow;

        // ---- phase 0: A frs 0,1 + all B; stage A(u+1)h0 ----
        #pragma unroll
        for (int q = 0; q < 2; ++q) {
            a[q][0] = *(const bf16x8*)(sa + q * 1024 + kx0);
            a[q][1] = *(const bf16x8*)(sa + q * 1024 + kx1);
        }
        #pragma unroll
        for (int fc = 0; fc < 4; ++fc) {
            bb[fc][0] = *(const bf16x8*)(sb + fc * 1024 + kx0);
            bb[fc][1] = *(const bf16x8*)(sb + fc * 1024 + kx1);
        }
        if (u >= 1 && u <= 6) STG(gA0, ASLOT(u + 1, 0), (u + 1) * 64);
        __builtin_amdgcn_s_barrier();
        LGKM0();
        PHASE_MFMA(0);
        __builtin_amdgcn_s_barrier();

        // ---- phase 1: A frs 2,3; stage A(u+1)h1, B(u+2)h0 ----
        #pragma unroll
        for (int q = 0; q < 2; ++q) {
            a[q][0] = *(const bf16x8*)(sa + (2 + q) * 1024 + kx0);
            a[q][1] = *(const bf16x8*)(sa + (2 + q) * 1024 + kx1);
        }
        if (u >= 1 && u <= 6) STG(gA1, ASLOT(u + 1, 1), (u + 1) * 64);
        if (u <= 5)           STG(gB0, BSLOT(u + 2, 0), (u + 2) * 64);
        __builtin_amdgcn_s_barrier();
        LGKM0();
        PHASE_MFMA(1);
        __builtin_amdgcn_s_barrier();

        // ---- phase 2: A frs 4,5; stage B(u+2)h1 ----
        #pragma unroll
        for (int q = 0; q < 2; ++q) {
            a[q][0] = *(const bf16x8*)(sa + (4 + q) * 1024 + kx0);
            a[q][1] = *(const bf16x8*)(sa + (4 + q) * 1024 + kx1);
        }
        if (u <= 5) STG(gB1, BSLOT(u + 2, 1), (u + 2) * 64);
        __builtin_amdgcn_s_barrier();
        LGKM0();
        PHASE_MFMA(2);
        __builtin_amdgcn_s_barrier();

        // ---- phase 3: A frs 6,7; per-K-tile counted vmcnt before T-barrier ----
        #pragma unroll
        for (int q = 0; q < 2; ++q) {
            a[q][0] = *(const bf16x8*)(sa + (6 + q) * 1024 + kx0);
            a[q][1] = *(const bf16x8*)(sa + (6 + q) * 1024 + kx1);
        }
        __builtin_amdgcn_s_barrier();
        LGKM0();
        PHASE_MFMA(3);
        if (u <= 5)      VMWAIT(4);   // A(u+1),B(u+1) landed for next K-tile
        else if (u == 6) VMWAIT(0);   // drain before last K-tile
        __builtin_amdgcn_s_barrier();
    }

    // ---------- epilogue: 4 passes of 64x256 f32 LDS roundtrip (swizzled) ----
    float* lf = (float*)smem;
    const int rl  = tid >> 3;            // 0..63
    const int e0  = (tid & 7) * 8;
    const int xrr = (rl & 7) << 2;
    #pragma unroll
    for (int h4 = 0; h4 < 4; ++h4) {
        __syncthreads();
        if (wm == (h4 >> 1)) {
            #pragma unroll
            for (int q = 0; q < 4; ++q)
                #pragma unroll
                for (int fc = 0; fc < 4; ++fc)
                    #pragma unroll
                    for (int rr = 0; rr < 4; ++rr) {
                        int r = q * 16 + g * 4 + rr;
                        int c = wn * 64 + fc * 16 + mrow;
                        lf[r * 256 + (c ^ ((r & 7) << 2))] = acc[(h4 & 1) * 4 + q][fc][rr];
                    }
        }
        __syncthreads();
        const int rg = m0 + h4 * 64 + rl;
        const int bb2 = rg / NTOK;
        const int nn  = rg - bb2 * NTOK;
        const float* lrow = lf + rl * 256;
        #pragma unroll
        for (int cb = 0; cb < 4; ++cb) {
            const int c0 = cb * 64 + e0;
            float4 v0 = *(const float4*)(lrow + ((c0    ) ^ xrr));
            float4 v1 = *(const float4*)(lrow + ((c0 + 4) ^ xrr));
            float vv[8] = {v0.x, v0.y, v0.z, v0.w, v1.x, v1.y, v1.z, v1.w};
            const int colg = n0 + c0;
            if (mode == 1) {
                if (f32) {
                    float ob[8];
                    #pragma unroll
                    for (int j = 0; j < 8; j++)
                        ob[j] = vv[j] + ((const float*)bias)[colg + j];
                    float* o = (float*)out0 + (size_t)rg * 512 + colg;
                    *(float4*)o       = *(const float4*)&ob[0];
                    *(float4*)(o + 4) = *(const float4*)&ob[4];
                } else {
                    ushort t8[8];
                    #pragma unroll
                    for (int j = 0; j < 8; j++)
                        t8[j] = f2b(vv[j] + b2f(((const ushort*)bias)[colg + j]));
                    *(uint4*)((ushort*)out0 + (size_t)rg * 512 + colg) = *(const uint4*)t8;
                }
            } else {
                const int tz = colg >> 9;
                const size_t oadr =
                    (((size_t)bb2 * 8 + ((colg >> 6) & 7)) * NTOK + nn) * 64 + (colg & 63);
                ushort t8[8];
                if (tz == 0) {                      // q = relu
                    #pragma unroll
                    for (int j = 0; j < 8; j++) t8[j] = f2b(fmaxf(vv[j], 0.f));
                    *(uint4*)((ushort*)out0 + oadr) = *(const uint4*)t8;
                } else if (tz == 1) {               // k = relu(+pos_enc)
                    const int d0 = colg - 512;
                    #pragma unroll
                    for (int j = 0; j < 8; j++) {
                        float pe = f32 ? ((const float*)pos_enc)[(size_t)nn * 512 + d0 + j]
                                       : b2f(((const ushort*)pos_enc)[(size_t)nn * 512 + d0 + j]);
                        t8[j] = f2b(fmaxf(vv[j] + pe, 0.f));
                    }
                    *(uint4*)(out1 + oadr) = *(const uint4*)t8;
                } else {                            // v = identity
                    #pragma unroll
                    for (int j = 0; j < 8; j++) t8[j] = f2b(vv[j]);
                    *(uint4*)(out2 + oadr) = *(const uint4*)t8;
                }
            }
        }
    }
#undef STG
#undef PHASE_MFMA
}

// ============================================================================
// DIAGNOSTIC: the exact K-loop above, repeated 8x, epilogue = 16B checksum.
// Reads arbitrary (finite) bf16 from A/Bt, writes scratch only. Purpose:
// dur(this)/8 ~= per-dispatch K-loop cost; 180us - that = epilogue+prologue.
// ============================================================================
__global__ __launch_bounds__(512, 2) void gemm_kloop8(
    const ushort* __restrict__ A, const ushort* __restrict__ Bt,
    ushort* __restrict__ scratch, int ntn)
{
    __shared__ ushort smem[65536];   // 128 KiB

    const int tid = threadIdx.x;
    const int lam = tid & 63;
    const int w   = tid >> 6;
    const int wm  = w >> 2;
    const int wn  = w & 3;
    const int g    = lam >> 4;
    const int mrow = lam & 15;

    const int nwg = gridDim.x;
    const int q8  = nwg >> 3;
    const int bid = blockIdx.x;
    const int fid = (bid & 7) * q8 + (bid >> 3);
    const int tm = fid / ntn, tn = fid - tm * ntn;
    const int m0 = tm * 256, n0 = tn * 256;

    const int srow  = w * 16 + (lam >> 3);
    const int scol8 = 8 * ((lam & 7) ^ (lam >> 3));
    const ushort* gA0 = A  + (size_t)(m0 +       srow) * KDIM + scol8;
    const ushort* gA1 = A  + (size_t)(m0 + 128 + srow) * KDIM + scol8;
    const ushort* gB0 = Bt + (size_t)(n0 +       srow) * KDIM + scol8;
    const ushort* gB1 = Bt + (size_t)(n0 + 128 + srow) * KDIM + scol8;

    const int m7  = mrow & 7;
    const int kx0 = 8 * (g ^ m7);
    const int kx1 = 8 * ((4 + g) ^ m7);
    const int aRow = mrow * 64;
    const int bRow = ((wn & 1) * 64 + mrow) * 64;

    floatx4 acc[8][4];
    #pragma unroll
    for (int i = 0; i < 8; i++)
        #pragma unroll
        for (int j = 0; j < 4; j++) acc[i][j] = (floatx4)0.f;

#define STG(gp, sb, ko) do { \
    async_copy16(smem + (sb) + w * 1024,       (gp) + (ko)); \
    async_copy16(smem + (sb) + w * 1024 + 512, (gp) + 4096 + (ko)); } while (0)

    STG(gA0, ASLOT(0,0), 0);  STG(gA1, ASLOT(0,1), 0);
    STG(gB0, BSLOT(0,0), 0);  STG(gB1, BSLOT(0,1), 0);
    STG(gA0, ASLOT(1,0), 64); STG(gA1, ASLOT(1,1), 64);
    STG(gB0, BSLOT(1,0), 64); STG(gB1, BSLOT(1,1), 64);
    VMWAIT(8);
    __builtin_amdgcn_s_barrier();

    bf16x8 a[2][2], bb[4][2];

#define PHASE_MFMA(P) do { \
    __builtin_amdgcn_s_setprio(1); \
    _Pragma("unroll") \
    for (int q = 0; q < 2; ++q) \
        _Pragma("unroll") \
        for (int fc = 0; fc < 4; ++fc) { \
            acc[2*(P)+q][fc] = __builtin_amdgcn_mfma_f32_16x16x32_bf16( \
                a[q][0], bb[fc][0], acc[2*(P)+q][fc], 0, 0, 0); \
            acc[2*(P)+q][fc] = __builtin_amdgcn_mfma_f32_16x16x32_bf16( \
                a[q][1], bb[fc][1], acc[2*(P)+q][fc], 0, 0, 0); \
        } \
    __builtin_amdgcn_s_setprio(0); } while (0)

    #pragma unroll 1
    for (int rep = 0; rep < 8; ++rep) {
        #pragma unroll
        for (int u = 0; u < 8; ++u) {
            const ushort* sa = smem + ASLOT(u, wm) + aRow;
            const ushort* sb = smem + BSLOT(u, (wn >> 1)) + bRow;

            #pragma unroll
            for (int q = 0; q < 2; ++q) {
                a[q][0] = *(const bf16x8*)(sa + q * 1024 + kx0);
                a[q][1] = *(const bf16x8*)(sa + q * 1024 + kx1);
            }
            #pragma unroll
            for (int fc = 0; fc < 4; ++fc) {
                bb[fc][0] = *(const bf16x8*)(sb + fc * 1024 + kx0);
                bb[fc][1] = *(const bf16x8*)(sb + fc * 1024 + kx1);
            }
            if (u >= 1 && u <= 6) STG(gA0, ASLOT(u + 1, 0), (u + 1) * 64);
            __builtin_amdgcn_s_barrier();
            LGKM0();
            PHASE_MFMA(0);
            __builtin_amdgcn_s_barrier();

            #pragma unroll
            for (int q = 0; q < 2; ++q) {
                a[q][0] = *(const bf16x8*)(sa + (2 + q) * 1024 + kx0);
                a[q][1] = *(const bf16x8*)(sa + (2 + q) * 1024 + kx1);
            }
            if (u >= 1 && u <= 6) STG(gA1, ASLOT(u + 1, 1), (u + 1) * 64);
            if (u <= 5)           STG(gB0, BSLOT(u + 2, 0), (u + 2) * 64);
            __builtin_amdgcn_s_barrier();
            LGKM0();
            PHASE_MFMA(1);
            __builtin_amdgcn_s_barrier();

            #pragma unroll
            for (int q = 0; q < 2; ++q) {
                a[q][0] = *(const bf16x8*)(sa + (4 + q) * 1024 + kx0);
                a[q][1] = *(const bf16x8*)(sa + (4 + q) * 1024 + kx1);
            }
            if (u <= 5) STG(gB1, BSLOT(u + 2, 1), (u + 2) * 64);
            __builtin_amdgcn_s_barrier();
            LGKM0();
            PHASE_MFMA(2);
            __builtin_amdgcn_s_barrier();

            #pragma unroll
            for (int q = 0; q < 2; ++q) {
                a[q][0] = *(const bf16x8*)(sa + (6 + q) * 1024 + kx0);
                a[q][1] = *(const bf16x8*)(sa + (6 + q) * 1024 + kx1);
            }
            __builtin_amdgcn_s_barrier();
            LGKM0();
            PHASE_MFMA(3);
            if (u <= 5)      VMWAIT(4);
            else if (u == 6) VMWAIT(0);
            __builtin_amdgcn_s_barrier();
        }
    }

    // checksum epilogue: 16 B/thread, keeps every acc live
    floatx4 s = (floatx4)0.f;
    #pragma unroll
    for (int i = 0; i < 8; i++)
        #pragma unroll
        for (int j = 0; j < 4; j++) s += acc[i][j];
    *(float4*)(scratch + (size_t)fid * 4096 + tid * 8) = *(float4*)&s;
#undef STG
#undef PHASE_MFMA
}

// ---------- ctx = k^T v via MFMA (+ fused ksum), atomic fp32 accumulation ----------
#define SPLITS 7
#define NPER   (NTOK / SPLITS)   // 448 = 14 * 32

__global__ __launch_bounds__(256) void ctx_ksum(
    const ushort* __restrict__ kbuf, const ushort* __restrict__ vbuf,
    float* __restrict__ ctx, float* __restrict__ ksum)
{
    __shared__ ushort kT[64 * 32];    // [d][n] bf16, XOR-block swizzled
    __shared__ ushort vT[64 * 32];    // [e][n] bf16, XOR-block swizzled
    __shared__ float ks4[256];
    int bh = blockIdx.x, sp = blockIdx.y;
    int tid = threadIdx.x;
    int lane = tid & 63, wave = tid >> 6;
    int mrow = lane & 15, g = lane >> 4;
    int r = tid & 31, cblk = tid >> 5;       // staging: n-row r, d/e-octet cblk
    size_t base = ((size_t)bh * NTOK + sp * NPER) * 64;

    floatx4 acc[4];
    #pragma unroll
    for (int c = 0; c < 4; c++) acc[c] = (floatx4)0.f;
    float kpart = 0.f;
    int kd = tid >> 2, kq = tid & 3;

    for (int nc = 0; nc < NPER; nc += 32) {
        uint4 ku = *(const uint4*)(kbuf + base + (size_t)(nc + r) * 64 + cblk * 8);
        uint4 vu = *(const uint4*)(vbuf + base + (size_t)(nc + r) * 64 + cblk * 8);
        __syncthreads();                     // previous tile fully consumed
        const ushort* kp = (const ushort*)&ku;
        const ushort* vp = (const ushort*)&vu;
        #pragma unroll
        for (int j = 0; j < 8; j++) {
            int d = cblk * 8 + j;
            int blk = (r >> 3) ^ swz(d);
            kT[d * 32 + blk * 8 + (r & 7)] = kp[j];
            vT[d * 32 + blk * 8 + (r & 7)] = vp[j];
        }
        __syncthreads();
        {
            const ushort* p = &kT[kd * 32 + kq * 8];
            #pragma unroll
            for (int j = 0; j < 8; j++) kpart += b2f(p[j]);
        }
        int dr = wave * 16 + mrow;
        bf16x8 af = *(const bf16x8*)&kT[dr * 32 + (g ^ swz(dr)) * 8];
        #pragma unroll
        for (int c = 0; c < 4; c++) {
            int er = c * 16 + mrow;
            bf16x8 bf = *(const bf16x8*)&vT[er * 32 + (g ^ swz(er)) * 8];
            acc[c] = __builtin_amdgcn_mfma_f32_16x16x32_bf16(af, bf, acc[c], 0, 0, 0);
        }
    }
    #pragma unroll
    for (int c = 0; c < 4; c++)
        #pragma unroll
        for (int rr = 0; rr < 4; rr++) {
            int d = wave * 16 + g * 4 + rr;
            int e = c * 16 + mrow;
            atomicAdd(&ctx[bh * 4096 + d * 64 + e], acc[c][rr]);
        }
    ks4[tid] = kpart;
    __syncthreads();
    if (tid < 64) {
        float s = ks4[tid * 4] + ks4[tid * 4 + 1] + ks4[tid * 4 + 2] + ks4[tid * 4 + 3];
        atomicAdd(&ksum[bh * 64 + tid], s);
    }
}

// ---------- attn = (q @ ctx) * d_inv via MFMA -> ybuf ----------
__global__ __launch_bounds__(256) void attn_kernel(
    const ushort* __restrict__ q, const float* __restrict__ ctx,
    const float* __restrict__ ksum, ushort* __restrict__ ybuf)
{
    __shared__ float smem[4352];             // 17408 B; ctxT (10240 B) aliases sout
    ushort* ctxT = (ushort*)smem;            // [80 e][64 d] bf16, 8-block swizzle
    float* sout = smem;                      // [64][68] fp32 epilogue
    int bh = blockIdx.x, cg = blockIdx.y;
    int tid = threadIdx.x;
    int lane = tid & 63, wave = tid >> 6;
    int mrow = lane & 15, g = lane >> 4;

    for (int i = tid; i < 640; i += 256) {
        int e = i >> 3, blk = i & 7;
        ushort tmp[8];
        #pragma unroll
        for (int j = 0; j < 8; j++) {
            int d = blk * 8 + j;
            float v = 0.f;
            if (e < 64) v = ctx[bh * 4096 + d * 64 + e];
            else if (e == 64) v = ksum[bh * 64 + d];
            tmp[j] = f2b(v);
        }
        *(uint4*)&ctxT[e * 64 + (blk ^ (e & 7)) * 8] = *(const uint4*)tmp;
    }
    __syncthreads();

    bf16x8 bfr[2][5];
    #pragma unroll
    for (int kt = 0; kt < 2; kt++)
        #pragma unroll
        for (int c = 0; c < 5; c++) {
            int e = c * 16 + mrow;
            bfr[kt][c] = *(const bf16x8*)&ctxT[e * 64 + ((kt * 4 + g) ^ (e & 7)) * 8];
        }

    int token4 = tid >> 2, seg = tid & 3;
    for (int cc = 0; cc < 7; cc++) {
        int n0 = (cg * 7 + cc) * 64;
        floatx4 acc[5];
        #pragma unroll
        for (int c = 0; c < 5; c++) acc[c] = (floatx4)0.f;
        size_t qrow = ((size_t)bh * NTOK + n0 + wave * 16 + mrow) * 64;
        #pragma unroll
        for (int kt = 0; kt < 2; kt++) {
            bf16x8 af = *(const bf16x8*)(q + qrow + kt * 32 + g * 8);
            #pragma unroll
            for (int c = 0; c < 5; c++)
                acc[c] = __builtin_amdgcn_mfma_f32_16x16x32_bf16(af, bfr[kt][c], acc[c], 0, 0, 0);
        }
        __syncthreads();
        #pragma unroll
        for (int c = 0; c < 4; c++)
            #pragma unroll
            for (int rr = 0; rr < 4; rr++)
                sout[(wave * 16 + g * 4 + rr) * 68 + c * 16 + mrow] = acc[c][rr];
        if (mrow == 0) {
            #pragma unroll
            for (int rr = 0; rr < 4; rr++)
                sout[(wave * 16 + g * 4 + rr) * 68 + 64] = acc[4][rr];
        }
        __syncthreads();
        float dinv = 1.0f / (sout[token4 * 68 + 64] + 1e-6f);
        const float* sp = &sout[token4 * 68 + seg * 16];
        ushort res[16];
        #pragma unroll
        for (int j = 0; j < 16; j++) res[j] = f2b(sp[j] * dinv);
        ushort* o = ybuf + ((size_t)bh * NTOK + n0 + token4) * 64 + seg * 16;
        *(uint4*)o = *(const uint4*)res;
        *(uint4*)(o + 8) = *(const uint4*)(res + 8);
    }
}

// ---------- y += depthwise 5x5 conv(v) + bias ----------
__global__ __launch_bounds__(256) void dwc_add(
    const ushort* __restrict__ v, const float* __restrict__ wT,
    ushort* __restrict__ ybuf)
{
    __shared__ float wls[1664];
    for (int i = threadIdx.x; i < 1664; i += 256) wls[i] = wT[i];
    __syncthreads();

    int t = blockIdx.x * 256 + threadIdx.x;
    int eg = (t & 7) * 8;
    int r = t >> 3;
    int n  = r % NTOK;
    int bh = r / NTOK;
    int y = n / HSP, x = n % HSP;

    float acc[8];
    #pragma unroll
    for (int j = 0; j < 8; j++) acc[j] = wls[1600 + eg + j];

    const ushort* vb = v + (size_t)bh * NTOK * 64 + eg;
    #pragma unroll
    for (int dy = 0; dy < 5; ++dy) {
        int yy = y + dy - 2;
        if (yy < 0 || yy >= HSP) continue;
        #pragma unroll
        for (int dx = 0; dx < 5; ++dx) {
            int xx = x + dx - 2;
            if (xx < 0 || xx >= HSP) continue;
            uint4 u = *(const uint4*)(vb + (size_t)(yy * HSP + xx) * 64);
            const ushort* up = (const ushort*)&u;
            const float* wp = &wls[(dy * 5 + dx) * 64 + eg];
            #pragma unroll
            for (int j = 0; j < 8; j++) acc[j] += wp[j] * b2f(up[j]);
        }
    }
    size_t o = (size_t)r * 64 + eg;
    uint4 yo = *(const uint4*)(ybuf + o);
    const ushort* yp = (const ushort*)&yo;
    ushort res[8];
    #pragma unroll
    for (int j = 0; j < 8; j++) res[j] = f2b(acc[j] + b2f(yp[j]));
    *(uint4*)(ybuf + o) = *(const uint4*)res;
}

// ---------- launch ----------
extern "C" void kernel_launch(void* const* d_in, const int* in_sizes, int n_in,
                              void* d_out, int out_size, void* d_ws, size_t ws_size,
                              hipStream_t stream) {
    const void* x    = d_in[0];
    const void* Wq   = d_in[1];
    const void* Wkv  = d_in[2];
    const void* pos  = d_in[3];
    const void* dwcw = d_in[4];
    const void* dwcb = d_in[5];
    const void* Wp   = d_in[6];
    const void* bp   = d_in[7];

    char* ws = (char*)d_ws;
    const size_t SZ_BIG = 51380224;                    // 50176*512*2
    int*    flag   = (int*)(ws + 0);
    ushort* WqkvT  = (ushort*)(ws + 4096);
    ushort* WpT    = (ushort*)(ws + 4096 + 1572864);
    float*  wTdwc  = (float*)(ws + 2101248);
    float*  ctx    = (float*)(ws + 2107904);
    float*  ksum   = (float*)(ws + 4205056);
    ushort* qbuf   = (ushort*)(ws + 4237824);
    ushort* kbuf   = (ushort*)(ws + 4237824 + SZ_BIG);     // reused as y
    ushort* vbuf   = (ushort*)(ws + 4237824 + 2 * SZ_BIG);
    ushort* xbf = (ushort*)d_out;   // dead until gemm2's final write

    detect_dtype<<<1, 256, 0, stream>>>((const ushort*)x, flag);
    hipMemsetAsync(ctx, 0, 2097152 + 32768, stream);

    prep_weights<<<4096, 256, 0, stream>>>(Wq, Wkv, Wp, flag, WqkvT, WpT);
    prep_dwc<<<1, 256, 0, stream>>>(dwcw, dwcb, flag, wTdwc);
    convert_x<<<12544, 256, 0, stream>>>(x, flag, xbf);

    // GEMM1: [50176,512] @ [512,1536] -> fused q/k/v epilogue
    gemm256_bt<<<dim3(196 * 6), 512, 0, stream>>>(
        xbf, WqkvT, 0, flag, pos, nullptr, qbuf, kbuf, vbuf, 6);

    ctx_ksum<<<dim3(128, SPLITS), 256, 0, stream>>>(kbuf, vbuf, ctx, ksum);

    attn_kernel<<<dim3(128, 7), 256, 0, stream>>>(qbuf, ctx, ksum, kbuf);

    dwc_add<<<12544, 256, 0, stream>>>(vbuf, wTdwc, kbuf);

    // GEMM2: [50176,512] @ [512,512] + bias -> d_out
    gemm256_bt<<<dim3(196 * 2), 512, 0, stream>>>(
        kbuf, WpT, 1, flag, nullptr, bp, d_out, nullptr, nullptr, 2);

    // DIAGNOSTIC (scratch-only; reads dead y-buffer + weights, writes qbuf):
    // dur/8 ~= K-loop cost of one gemm1-shaped dispatch.
    gemm_kloop8<<<dim3(196 * 6), 512, 0, stream>>>(kbuf, WqkvT, qbuf, 6);
}

// Round 7
// 537.046 us; speedup vs baseline: 2.0962x; 2.0962x over previous
//
#include <hip/hip_runtime.h>

// ---------- bf16 helpers (raw ushort representation) ----------
__device__ __forceinline__ float b2f(ushort u) {
    union { float f; unsigned int i; } w; w.i = ((unsigned int)u) << 16; return w.f;
}
__device__ __forceinline__ ushort f2b(float f) {
    union { float f; unsigned int i; } w; w.f = f;
    unsigned int lsb = (w.i >> 16) & 1u;
    w.i += 0x7fffu + lsb;
    return (ushort)(w.i >> 16);
}

typedef __bf16 bf16x8 __attribute__((ext_vector_type(8)));
typedef float floatx4 __attribute__((ext_vector_type(4)));

// async global->LDS, 16B per lane; lane i lands at lds_base + i*16B (HW rule)
__device__ __forceinline__ void async_copy16(ushort* lds_base, const ushort* gptr) {
    __builtin_amdgcn_global_load_lds(
        (const __attribute__((address_space(1))) unsigned int*)gptr,
        (__attribute__((address_space(3))) unsigned int*)lds_base,
        16, 0, 0);
}

// Problem constants
#define BATCH 16
#define NTOK  3136
#define NHEAD 8
#define HDIM  64
#define HSP   56
#define MROWS (BATCH * NTOK)   // 50176
#define KDIM  512              // both GEMMs have K = 512

// ---------- dtype detection ----------
__global__ __launch_bounds__(256) void detect_dtype(const ushort* __restrict__ x,
                                                    int* __restrict__ flag)
{
    __shared__ int s;
    if (threadIdx.x == 0) s = 0;
    __syncthreads();
    int bad = 0;
    for (int i = threadIdx.x; i < 4096; i += 256) {
        int e = (x[i] >> 7) & 0xFF;
        if (e >= 0x90) bad = 1;
    }
    if (bad) s = 1;
    __syncthreads();
    if (threadIdx.x == 0) flag[0] = s;   // 1 => inputs are fp32
}

// ---------- convert x -> bf16 ----------
__global__ __launch_bounds__(256) void convert_x(
    const void* __restrict__ x, const int* __restrict__ flag,
    ushort* __restrict__ xbf)
{
    size_t t = (size_t)blockIdx.x * 256 + threadIdx.x;
    if (flag[0]) {
        const float* xf = (const float*)x + t * 8;
        float4 f0 = *(const float4*)xf;
        float4 f1 = *(const float4*)(xf + 4);
        ushort o[8] = { f2b(f0.x), f2b(f0.y), f2b(f0.z), f2b(f0.w),
                        f2b(f1.x), f2b(f1.y), f2b(f1.z), f2b(f1.w) };
        *(uint4*)(xbf + t * 8) = *(const uint4*)o;
    } else {
        *(uint4*)(xbf + t * 8) = *((const uint4*)x + t);
    }
}

// ---------- weight transpose ----------
__global__ __launch_bounds__(256) void prep_weights(
    const void* __restrict__ Wq, const void* __restrict__ Wkv,
    const void* __restrict__ Wp, const int* __restrict__ flag,
    ushort* __restrict__ WqkvT, ushort* __restrict__ WpT)
{
    bool f32 = flag[0] != 0;
    int idx = blockIdx.x * 256 + threadIdx.x;
    int kk = idx & 511;
    int n  = idx >> 9;
    if (n < 1536) {
        ushort val;
        if (n < 512)
            val = f32 ? f2b(((const float*)Wq)[kk * 512 + n])
                      : ((const ushort*)Wq)[kk * 512 + n];
        else
            val = f32 ? f2b(((const float*)Wkv)[kk * 1024 + (n - 512)])
                      : ((const ushort*)Wkv)[kk * 1024 + (n - 512)];
        WqkvT[n * 512 + kk] = val;
    } else {
        int n2 = n - 1536;
        WpT[n2 * 512 + kk] = f32 ? f2b(((const float*)Wp)[kk * 512 + n2])
                                 : ((const ushort*)Wp)[kk * 512 + n2];
    }
}

// ---------- prep dwc weights ----------
__global__ __launch_bounds__(256) void prep_dwc(
    const void* __restrict__ dwc_w, const void* __restrict__ dwc_b,
    const int* __restrict__ flag, float* __restrict__ wT)
{
    bool f32 = flag[0] != 0;
    for (int i = threadIdx.x; i < 1600; i += 256) {
        int e = i / 25, tap = i % 25;
        float w = f32 ? ((const float*)dwc_w)[i] : b2f(((const ushort*)dwc_w)[i]);
        wT[tap * 64 + e] = w;
    }
    if (threadIdx.x < 64) {
        float b = f32 ? ((const float*)dwc_b)[threadIdx.x]
                      : b2f(((const ushort*)dwc_b)[threadIdx.x]);
        wT[1600 + threadIdx.x] = b;
    }
}

__device__ __forceinline__ int swz(int r) { return (r ^ (r >> 2)) & 3; }

// ============================================================================
// 256x256 8-wave GEMM, BK=64, 4-phase deep-prefetch K-loop (R5-verified),
// with OPERAND-SWAPPED MFMA so the accumulator is store-shaped:
//   acc[fr][fc] = mfma(bb, a, acc)  =>  lane l, reg r holds
//     C[row = m0 + wm*128 + fr*16 + (l&15)]
//      [col = n0 + wn*64 + fc*16 + (l>>4)*4 + r]
// i.e. each lane owns one output ROW with 4 consecutive cols per reg quad.
// Epilogue: direct per-lane 8B/16B stores (relu/pos_enc/bias in regs),
// NO LDS roundtrip, NO syncthreads (R6 diag: old epilogue was 21 us/block
// vs K-loop 18 us/block — 54% of gemm time).
//
// K-loop staging/swizzle/vmcnt ledger identical to R5 (see R5 comments):
// LDS 128 KiB, per operand 4 half-slots of 128x64 bf16, chunk swizzle
// c16 ^ (r&7) with inverse-swizzled global source (0 bank conflicts).
// vmcnt: prologue 16 loads -> VMWAIT(8); ph3(u<=5) VMWAIT(4); u==6 VMWAIT(0).
// ============================================================================
#define VMWAIT(N) asm volatile("s_waitcnt vmcnt(" #N ")" ::: "memory")
#define LGKM0()   do { asm volatile("s_waitcnt lgkmcnt(0)" ::: "memory"); \
                       __builtin_amdgcn_sched_barrier(0); } while (0)
#define ASLOT(u,h) ((((u) & 1) * 2 + (h)) * 8192)
#define BSLOT(u,h) (32768 + (((u) & 1) * 2 + (h)) * 8192)

__global__ __launch_bounds__(512, 2) void gemm256_bt(
    const ushort* __restrict__ A, const ushort* __restrict__ Bt,
    int mode, const int* __restrict__ flag,
    const void* __restrict__ pos_enc, const void* __restrict__ bias,
    void* __restrict__ out0, ushort* __restrict__ out1, ushort* __restrict__ out2,
    int ntn)
{
    __shared__ ushort smem[65536];   // 128 KiB

    const bool f32 = flag[0] != 0;
    const int tid = threadIdx.x;
    const int lam = tid & 63;
    const int w   = tid >> 6;        // 0..7
    const int wm  = w >> 2;          // 0..1 (M half)
    const int wn  = w & 3;           // 0..3 (N quarter)
    const int g    = lam >> 4;       // 0..3
    const int mrow = lam & 15;

    // XCD-aware bijective swizzle, tm-major (consecutive fid share A-panel)
    const int nwg = gridDim.x;
    const int q8  = nwg >> 3;
    const int bid = blockIdx.x;
    const int fid = (bid & 7) * q8 + (bid >> 3);
    const int tm = fid / ntn, tn = fid - tm * ntn;
    const int m0 = tm * 256, n0 = tn * 256;

    // staging: per-lane pointers, inverse-swizzled global column (R1-proven)
    const int srow  = w * 16 + (lam >> 3);            // row within 128-row half
    const int scol8 = 8 * ((lam & 7) ^ (lam >> 3));   // pre-swizzled col (elems)
    const ushort* gA0 = A  + (size_t)(m0 +       srow) * KDIM + scol8;
    const ushort* gA1 = A  + (size_t)(m0 + 128 + srow) * KDIM + scol8;
    const ushort* gB0 = Bt + (size_t)(n0 +       srow) * KDIM + scol8;
    const ushort* gB1 = Bt + (size_t)(n0 + 128 + srow) * KDIM + scol8;

    // fragment read offsets (ushort units): row r -> r*64 + ((c ^ (r&7))*8)
    const int m7  = mrow & 7;
    const int kx0 = 8 * (g ^ m7);          // k-step 0 (chunks 0..3)
    const int kx1 = 8 * ((4 + g) ^ m7);    // k-step 1 (chunks 4..7)
    const int aRow = mrow * 64;                         // + fr*1024
    const int bRow = ((wn & 1) * 64 + mrow) * 64;       // + fc*1024

    floatx4 acc[8][4];
    #pragma unroll
    for (int i = 0; i < 8; i++)
        #pragma unroll
        for (int j = 0; j < 4; j++) acc[i][j] = (floatx4)0.f;

#define STG(gp, sb, ko) do { \
    async_copy16(smem + (sb) + w * 1024,       (gp) + (ko)); \
    async_copy16(smem + (sb) + w * 1024 + 512, (gp) + 4096 + (ko)); } while (0)

    // prologue: K-tiles 0 and 1
    STG(gA0, ASLOT(0,0), 0);  STG(gA1, ASLOT(0,1), 0);
    STG(gB0, BSLOT(0,0), 0);  STG(gB1, BSLOT(0,1), 0);
    STG(gA0, ASLOT(1,0), 64); STG(gA1, ASLOT(1,1), 64);
    STG(gB0, BSLOT(1,0), 64); STG(gB1, BSLOT(1,1), 64);
    VMWAIT(8);                       // A(0),B(0) landed (K-tile 1 in flight)
    __builtin_amdgcn_s_barrier();

    bf16x8 a[2][2], bb[4][2];

// SWAPPED operand order: mfma(bb, a) -> store-shaped accumulator
#define PHASE_MFMA(P) do { \
    __builtin_amdgcn_s_setprio(1); \
    _Pragma("unroll") \
    for (int q = 0; q < 2; ++q) \
        _Pragma("unroll") \
        for (int fc = 0; fc < 4; ++fc) { \
            acc[2*(P)+q][fc] = __builtin_amdgcn_mfma_f32_16x16x32_bf16( \
                bb[fc][0], a[q][0], acc[2*(P)+q][fc], 0, 0, 0); \
            acc[2*(P)+q][fc] = __builtin_amdgcn_mfma_f32_16x16x32_bf16( \
                bb[fc][1], a[q][1], acc[2*(P)+q][fc], 0, 0, 0); \
        } \
    __builtin_amdgcn_s_setprio(0); } while (0)

    #pragma unroll
    for (int u = 0; u < 8; ++u) {
        const ushort* sa = smem + ASLOT(u, wm) + aRow;
        const ushort* sb = smem + BSLOT(u, (wn >> 1)) + bRow;

        // ---- phase 0: A frs 0,1 + all B; stage A(u+1)h0 ----
        #pragma unroll
        for (int q = 0; q < 2; ++q) {
            a[q][0] = *(const bf16x8*)(sa + q * 1024 + kx0);
            a[q][1] = *(const bf16x8*)(sa + q * 1024 + kx1);
        }
        #pragma unroll
        for (int fc = 0; fc < 4; ++fc) {
            bb[fc][0] = *(const bf16x8*)(sb + fc * 1024 + kx0);
            bb[fc][1] = *(const bf16x8*)(sb + fc * 1024 + kx1);
        }
        if (u >= 1 && u <= 6) STG(gA0, ASLOT(u + 1, 0), (u + 1) * 64);
        __builtin_amdgcn_s_barrier();
        LGKM0();
        PHASE_MFMA(0);
        __builtin_amdgcn_s_barrier();

        // ---- phase 1: A frs 2,3; stage A(u+1)h1, B(u+2)h0 ----
        #pragma unroll
        for (int q = 0; q < 2; ++q) {
            a[q][0] = *(const bf16x8*)(sa + (2 + q) * 1024 + kx0);
            a[q][1] = *(const bf16x8*)(sa + (2 + q) * 1024 + kx1);
        }
        if (u >= 1 && u <= 6) STG(gA1, ASLOT(u + 1, 1), (u + 1) * 64);
        if (u <= 5)           STG(gB0, BSLOT(u + 2, 0), (u + 2) * 64);
        __builtin_amdgcn_s_barrier();
        LGKM0();
        PHASE_MFMA(1);
        __builtin_amdgcn_s_barrier();

        // ---- phase 2: A frs 4,5; stage B(u+2)h1 ----
        #pragma unroll
        for (int q = 0; q < 2; ++q) {
            a[q][0] = *(const bf16x8*)(sa + (4 + q) * 1024 + kx0);
            a[q][1] = *(const bf16x8*)(sa + (4 + q) * 1024 + kx1);
        }
        if (u <= 5) STG(gB1, BSLOT(u + 2, 1), (u + 2) * 64);
        __builtin_amdgcn_s_barrier();
        LGKM0();
        PHASE_MFMA(2);
        __builtin_amdgcn_s_barrier();

        // ---- phase 3: A frs 6,7; per-K-tile counted vmcnt before T-barrier ----
        #pragma unroll
        for (int q = 0; q < 2; ++q) {
            a[q][0] = *(const bf16x8*)(sa + (6 + q) * 1024 + kx0);
            a[q][1] = *(const bf16x8*)(sa + (6 + q) * 1024 + kx1);
        }
        __builtin_amdgcn_s_barrier();
        LGKM0();
        PHASE_MFMA(3);
        if (u <= 5)      VMWAIT(4);   // A(u+1),B(u+1) landed for next K-tile
        else if (u == 6) VMWAIT(0);   // drain before last K-tile
        if (u < 7) __builtin_amdgcn_s_barrier();  // no barrier after last phase:
                                                  // epilogue is wave-independent
    }

    // ---------- epilogue: direct per-lane stores, no LDS, no syncs ----------
    // lane l, frag (fr,fc), reg r:
    //   row = m0 + wm*128 + fr*16 + (l&15); col = n0 + wn*64 + fc*16 + g*4 + r
    const int cb0 = n0 + wn * 64;          // wave col base (multiple of 64)
    #pragma unroll
    for (int fr = 0; fr < 8; ++fr) {
        const int rg  = m0 + wm * 128 + fr * 16 + mrow;
        const int bb2 = rg / NTOK;
        const int nn  = rg - bb2 * NTOK;
        if (mode == 1) {
            if (f32) {
                float* orow = (float*)out0 + (size_t)rg * 512 + cb0 + g * 4;
                #pragma unroll
                for (int fc = 0; fc < 4; ++fc) {
                    float ob[4];
                    #pragma unroll
                    for (int r = 0; r < 4; ++r)
                        ob[r] = acc[fr][fc][r] +
                                ((const float*)bias)[cb0 + fc * 16 + g * 4 + r];
                    *(float4*)(orow + fc * 16) = *(const float4*)ob;
                }
            } else {
                ushort* orow = (ushort*)out0 + (size_t)rg * 512 + cb0 + g * 4;
                #pragma unroll
                for (int fc = 0; fc < 4; ++fc) {
                    ushort t4[4];
                    #pragma unroll
                    for (int r = 0; r < 4; ++r)
                        t4[r] = f2b(acc[fr][fc][r] +
                                    b2f(((const ushort*)bias)[cb0 + fc * 16 + g * 4 + r]));
                    *(uint2*)(orow + fc * 16) = *(const uint2*)t4;
                }
            }
        } else {
            const int tz   = cb0 >> 9;             // block-uniform output class
            const int head = (cb0 >> 6) & 7;       // wave-uniform head
            const size_t obase =
                (((size_t)bb2 * 8 + head) * NTOK + nn) * 64 + g * 4;
            if (tz == 0) {                          // q = relu
                #pragma unroll
                for (int fc = 0; fc < 4; ++fc) {
                    ushort t4[4];
                    #pragma unroll
                    for (int r = 0; r < 4; ++r)
                        t4[r] = f2b(fmaxf(acc[fr][fc][r], 0.f));
                    *(uint2*)((ushort*)out0 + obase + fc * 16) = *(const uint2*)t4;
                }
            } else if (tz == 1) {                   // k = relu(+pos_enc)
                const int d0 = cb0 - 512 + g * 4;
                #pragma unroll
                for (int fc = 0; fc < 4; ++fc) {
                    ushort t4[4];
                    #pragma unroll
                    for (int r = 0; r < 4; ++r) {
                        float pe = f32
                            ? ((const float*)pos_enc)[(size_t)nn * 512 + d0 + fc * 16 + r]
                            : b2f(((const ushort*)pos_enc)[(size_t)nn * 512 + d0 + fc * 16 + r]);
                        t4[r] = f2b(fmaxf(acc[fr][fc][r] + pe, 0.f));
                    }
                    *(uint2*)(out1 + obase + fc * 16) = *(const uint2*)t4;
                }
            } else {                                // v = identity
                #pragma unroll
                for (int fc = 0; fc < 4; ++fc) {
                    ushort t4[4];
                    #pragma unroll
                    for (int r = 0; r < 4; ++r)
                        t4[r] = f2b(acc[fr][fc][r]);
                    *(uint2*)(out2 + obase + fc * 16) = *(const uint2*)t4;
                }
            }
        }
    }
#undef STG
#undef PHASE_MFMA
}

// ---------- ctx = k^T v via MFMA (+ fused ksum), atomic fp32 accumulation ----------
#define SPLITS 7
#define NPER   (NTOK / SPLITS)   // 448 = 14 * 32

__global__ __launch_bounds__(256) void ctx_ksum(
    const ushort* __restrict__ kbuf, const ushort* __restrict__ vbuf,
    float* __restrict__ ctx, float* __restrict__ ksum)
{
    __shared__ ushort kT[64 * 32];    // [d][n] bf16, XOR-block swizzled
    __shared__ ushort vT[64 * 32];    // [e][n] bf16, XOR-block swizzled
    __shared__ float ks4[256];
    int bh = blockIdx.x, sp = blockIdx.y;
    int tid = threadIdx.x;
    int lane = tid & 63, wave = tid >> 6;
    int mrow = lane & 15, g = lane >> 4;
    int r = tid & 31, cblk = tid >> 5;       // staging: n-row r, d/e-octet cblk
    size_t base = ((size_t)bh * NTOK + sp * NPER) * 64;

    floatx4 acc[4];
    #pragma unroll
    for (int c = 0; c < 4; c++) acc[c] = (floatx4)0.f;
    float kpart = 0.f;
    int kd = tid >> 2, kq = tid & 3;

    for (int nc = 0; nc < NPER; nc += 32) {
        uint4 ku = *(const uint4*)(kbuf + base + (size_t)(nc + r) * 64 + cblk * 8);
        uint4 vu = *(const uint4*)(vbuf + base + (size_t)(nc + r) * 64 + cblk * 8);
        __syncthreads();                     // previous tile fully consumed
        const ushort* kp = (const ushort*)&ku;
        const ushort* vp = (const ushort*)&vu;
        #pragma unroll
        for (int j = 0; j < 8; j++) {
            int d = cblk * 8 + j;
            int blk = (r >> 3) ^ swz(d);
            kT[d * 32 + blk * 8 + (r & 7)] = kp[j];
            vT[d * 32 + blk * 8 + (r & 7)] = vp[j];
        }
        __syncthreads();
        {
            const ushort* p = &kT[kd * 32 + kq * 8];
            #pragma unroll
            for (int j = 0; j < 8; j++) kpart += b2f(p[j]);
        }
        int dr = wave * 16 + mrow;
        bf16x8 af = *(const bf16x8*)&kT[dr * 32 + (g ^ swz(dr)) * 8];
        #pragma unroll
        for (int c = 0; c < 4; c++) {
            int er = c * 16 + mrow;
            bf16x8 bf = *(const bf16x8*)&vT[er * 32 + (g ^ swz(er)) * 8];
            acc[c] = __builtin_amdgcn_mfma_f32_16x16x32_bf16(af, bf, acc[c], 0, 0, 0);
        }
    }
    #pragma unroll
    for (int c = 0; c < 4; c++)
        #pragma unroll
        for (int rr = 0; rr < 4; rr++) {
            int d = wave * 16 + g * 4 + rr;
            int e = c * 16 + mrow;
            atomicAdd(&ctx[bh * 4096 + d * 64 + e], acc[c][rr]);
        }
    ks4[tid] = kpart;
    __syncthreads();
    if (tid < 64) {
        float s = ks4[tid * 4] + ks4[tid * 4 + 1] + ks4[tid * 4 + 2] + ks4[tid * 4 + 3];
        atomicAdd(&ksum[bh * 64 + tid], s);
    }
}

// ---------- attn = (q @ ctx) * d_inv via MFMA -> ybuf ----------
__global__ __launch_bounds__(256) void attn_kernel(
    const ushort* __restrict__ q, const float* __restrict__ ctx,
    const float* __restrict__ ksum, ushort* __restrict__ ybuf)
{
    __shared__ float smem[4352];             // 17408 B; ctxT (10240 B) aliases sout
    ushort* ctxT = (ushort*)smem;            // [80 e][64 d] bf16, 8-block swizzle
    float* sout = smem;                      // [64][68] fp32 epilogue
    int bh = blockIdx.x, cg = blockIdx.y;
    int tid = threadIdx.x;
    int lane = tid & 63, wave = tid >> 6;
    int mrow = lane & 15, g = lane >> 4;

    for (int i = tid; i < 640; i += 256) {
        int e = i >> 3, blk = i & 7;
        ushort tmp[8];
        #pragma unroll
        for (int j = 0; j < 8; j++) {
            int d = blk * 8 + j;
            float v = 0.f;
            if (e < 64) v = ctx[bh * 4096 + d * 64 + e];
            else if (e == 64) v = ksum[bh * 64 + d];
            tmp[j] = f2b(v);
        }
        *(uint4*)&ctxT[e * 64 + (blk ^ (e & 7)) * 8] = *(const uint4*)tmp;
    }
    __syncthreads();

    bf16x8 bfr[2][5];
    #pragma unroll
    for (int kt = 0; kt < 2; kt++)
        #pragma unroll
        for (int c = 0; c < 5; c++) {
            int e = c * 16 + mrow;
            bfr[kt][c] = *(const bf16x8*)&ctxT[e * 64 + ((kt * 4 + g) ^ (e & 7)) * 8];
        }

    int token4 = tid >> 2, seg = tid & 3;
    for (int cc = 0; cc < 7; cc++) {
        int n0 = (cg * 7 + cc) * 64;
        floatx4 acc[5];
        #pragma unroll
        for (int c = 0; c < 5; c++) acc[c] = (floatx4)0.f;
        size_t qrow = ((size_t)bh * NTOK + n0 + wave * 16 + mrow) * 64;
        #pragma unroll
        for (int kt = 0; kt < 2; kt++) {
            bf16x8 af = *(const bf16x8*)(q + qrow + kt * 32 + g * 8);
            #pragma unroll
            for (int c = 0; c < 5; c++)
                acc[c] = __builtin_amdgcn_mfma_f32_16x16x32_bf16(af, bfr[kt][c], acc[c], 0, 0, 0);
        }
        __syncthreads();
        #pragma unroll
        for (int c = 0; c < 4; c++)
            #pragma unroll
            for (int rr = 0; rr < 4; rr++)
                sout[(wave * 16 + g * 4 + rr) * 68 + c * 16 + mrow] = acc[c][rr];
        if (mrow == 0) {
            #pragma unroll
            for (int rr = 0; rr < 4; rr++)
                sout[(wave * 16 + g * 4 + rr) * 68 + 64] = acc[4][rr];
        }
        __syncthreads();
        float dinv = 1.0f / (sout[token4 * 68 + 64] + 1e-6f);
        const float* sp = &sout[token4 * 68 + seg * 16];
        ushort res[16];
        #pragma unroll
        for (int j = 0; j < 16; j++) res[j] = f2b(sp[j] * dinv);
        ushort* o = ybuf + ((size_t)bh * NTOK + n0 + token4) * 64 + seg * 16;
        *(uint4*)o = *(const uint4*)res;
        *(uint4*)(o + 8) = *(const uint4*)(res + 8);
    }
}

// ---------- y += depthwise 5x5 conv(v) + bias ----------
__global__ __launch_bounds__(256) void dwc_add(
    const ushort* __restrict__ v, const float* __restrict__ wT,
    ushort* __restrict__ ybuf)
{
    __shared__ float wls[1664];
    for (int i = threadIdx.x; i < 1664; i += 256) wls[i] = wT[i];
    __syncthreads();

    int t = blockIdx.x * 256 + threadIdx.x;
    int eg = (t & 7) * 8;
    int r = t >> 3;
    int n  = r % NTOK;
    int bh = r / NTOK;
    int y = n / HSP, x = n % HSP;

    float acc[8];
    #pragma unroll
    for (int j = 0; j < 8; j++) acc[j] = wls[1600 + eg + j];

    const ushort* vb = v + (size_t)bh * NTOK * 64 + eg;
    #pragma unroll
    for (int dy = 0; dy < 5; ++dy) {
        int yy = y + dy - 2;
        if (yy < 0 || yy >= HSP) continue;
        #pragma unroll
        for (int dx = 0; dx < 5; ++dx) {
            int xx = x + dx - 2;
            if (xx < 0 || xx >= HSP) continue;
            uint4 u = *(const uint4*)(vb + (size_t)(yy * HSP + xx) * 64);
            const ushort* up = (const ushort*)&u;
            const float* wp = &wls[(dy * 5 + dx) * 64 + eg];
            #pragma unroll
            for (int j = 0; j < 8; j++) acc[j] += wp[j] * b2f(up[j]);
        }
    }
    size_t o = (size_t)r * 64 + eg;
    uint4 yo = *(const uint4*)(ybuf + o);
    const ushort* yp = (const ushort*)&yo;
    ushort res[8];
    #pragma unroll
    for (int j = 0; j < 8; j++) res[j] = f2b(acc[j] + b2f(yp[j]));
    *(uint4*)(ybuf + o) = *(const uint4*)res;
}

// ---------- launch ----------
extern "C" void kernel_launch(void* const* d_in, const int* in_sizes, int n_in,
                              void* d_out, int out_size, void* d_ws, size_t ws_size,
                              hipStream_t stream) {
    const void* x    = d_in[0];
    const void* Wq   = d_in[1];
    const void* Wkv  = d_in[2];
    const void* pos  = d_in[3];
    const void* dwcw = d_in[4];
    const void* dwcb = d_in[5];
    const void* Wp   = d_in[6];
    const void* bp   = d_in[7];

    char* ws = (char*)d_ws;
    const size_t SZ_BIG = 51380224;                    // 50176*512*2
    int*    flag   = (int*)(ws + 0);
    ushort* WqkvT  = (ushort*)(ws + 4096);
    ushort* WpT    = (ushort*)(ws + 4096 + 1572864);
    float*  wTdwc  = (float*)(ws + 2101248);
    float*  ctx    = (float*)(ws + 2107904);
    float*  ksum   = (float*)(ws + 4205056);
    ushort* qbuf   = (ushort*)(ws + 4237824);
    ushort* kbuf   = (ushort*)(ws + 4237824 + SZ_BIG);     // reused as y
    ushort* vbuf   = (ushort*)(ws + 4237824 + 2 * SZ_BIG);
    ushort* xbf = (ushort*)d_out;   // dead until gemm2's final write

    detect_dtype<<<1, 256, 0, stream>>>((const ushort*)x, flag);
    hipMemsetAsync(ctx, 0, 2097152 + 32768, stream);

    prep_weights<<<4096, 256, 0, stream>>>(Wq, Wkv, Wp, flag, WqkvT, WpT);
    prep_dwc<<<1, 256, 0, stream>>>(dwcw, dwcb, flag, wTdwc);
    convert_x<<<12544, 256, 0, stream>>>(x, flag, xbf);

    // GEMM1: [50176,512] @ [512,1536] -> fused q/k/v epilogue
    gemm256_bt<<<dim3(196 * 6), 512, 0, stream>>>(
        xbf, WqkvT, 0, flag, pos, nullptr, qbuf, kbuf, vbuf, 6);

    ctx_ksum<<<dim3(128, SPLITS), 256, 0, stream>>>(kbuf, vbuf, ctx, ksum);

    attn_kernel<<<dim3(128, 7), 256, 0, stream>>>(qbuf, ctx, ksum, kbuf);

    dwc_add<<<12544, 256, 0, stream>>>(vbuf, wTdwc, kbuf);

    // GEMM2: [50176,512] @ [512,512] + bias -> d_out
    gemm256_bt<<<dim3(196 * 2), 512, 0, stream>>>(
        kbuf, WpT, 1, flag, nullptr, bp, d_out, nullptr, nullptr, 2);
}